// Round 8
// baseline (122.012 us; speedup 1.0000x reference)
//
#include <hip/hip_runtime.h>

// COO SpMM: out[r,:] = sum_e vals[e] * seq[cols[e],:], rows sorted.
// N=50000, E=1.25M, D=64, fp32 in/out.
//
// R1-R5: gather-geometry ladder               -> 56.6 .. 53 us
// R6: RPS=1, depth 8, fp32 direct             -> ~41 us spmm
// R7: bf16 gather table (6.4 MB)              -> harness 98.6 (best total)
// R8: concurrent feature-split halves         -> 111 FAIL (XCD parity myth)
// R9: temporal column partition (2 phases)    -> 126 FAIL; KEY: phase with
//     L2-RESIDENT 3.2MB table still 37 us => residency is a non-lever.
// R10: halved vmem instrs + meta prefetch     -> 103 (no spmm gain)
// R11: 32-lane subs                           -> 113.6 FAIL (geometry broke it)
// R12: fp32 direct + row_ptr prep, PROFILED: spmm 45.2 us, FETCH 133MB,
//     3.2 TB/s, VALU 18%, occ 60%. Total 117 but component sum ~92 =>
//     ~25 us of dispatch-gap/noise.
//
// LEDGER: 8 formulations spanning 2x bytes, 2x txns, 4x instrs, resident
//   vs not => spmm floor 37-45 us. Memory-side levers are exhausted.
//   Remaining addressable term: dispatch count / launch gaps.
// R13 (this): ONE dispatch. row_start via in-kernel binary search over
//   sorted rows[] (lanes 0..4 lower-bound the wave's 5 row boundaries;
//   ~21 L2-hot dependent loads, hidden under other waves' gathers).
//   Gather loop identical to R12/R6. No workspace use at all.

#define WPB 4               // waves per 256-thread block

__global__ __launch_bounds__(256) void spmm_kernel(
    const float4* __restrict__ seq,       // [N][16] float4 = [N][64] fp32
    const float* __restrict__ vals,       // [E]
    const int*   __restrict__ cols,       // [E]
    const int*   __restrict__ rows,       // [E] sorted
    float*       __restrict__ out,        // [N, 64] fp32
    int n_nodes, int n_edges)
{
    const int lane = threadIdx.x & 63;
    const int sub  = lane >> 4;           // 16-lane sub-wave id (0..3)
    const int fl   = lane & 15;           // float4 slot: feats 4*fl..4*fl+3
    const int ml   = fl & 7;              // meta slot within chunk of 8
    const int wave = blockIdx.x * WPB + (threadIdx.x >> 6);

    const int base = wave * 4;            // this wave's first row
    if (base >= n_nodes) return;          // wave-uniform exit

    // Per-wave row boundaries: lanes 0..4 lower-bound rows[] for
    // targets base..base+4 (all 64 lanes run the search on a clamped
    // target to stay convergent; only 0..4 are consumed).
    int target = base + (lane < 4 ? lane : 4);
    if (target > n_nodes) target = n_nodes;
    int lo = 0, hi = n_edges;
    while (lo < hi) {                     // first idx with rows[idx] >= target
        const int mid = (lo + hi) >> 1;
        if (rows[mid] < target) lo = mid + 1;
        else                    hi = mid;
    }

    const int r = base + sub;             // one row per 16-lane sub
    const bool valid = (r < n_nodes);

    int e     = __shfl(lo, sub);
    int e_end = __shfl(lo, sub + 1);
    if (!valid) { e = 0; e_end = 0; }

    float4 acc = make_float4(0.f, 0.f, 0.f, 0.f);

    while (__any(e < e_end)) {
        // coalesced metadata: next 8 edges of this sub
        // (lanes 8..15 load duplicates; only lanes 0..7 used as sources)
        int cidx = e + ml;
        if (cidx >= n_edges) cidx = n_edges - 1;
        if (cidx < 0)        cidx = 0;
        const int   c = cols[cidx];
        const float v = vals[cidx];

        // 8 independent gathers; each instr = 64 lanes x 16 B = 4 rows
        // of 256 B (0.25 vmem instr/edge). Whole chunk in one latency
        // round; a sub's 16 lanes read one full fp32 row.
        float4 x[8];
#pragma unroll
        for (int u = 0; u < 8; ++u) {
            const int cu = __shfl(c, (sub << 4) | u);   // sub-local bcast
            if (e + u < e_end)
                x[u] = seq[(cu << 4) + fl];             // 16 B: 4 fp32 feats
        }
#pragma unroll
        for (int u = 0; u < 8; ++u) {
            const float vu = __shfl(v, (sub << 4) | u);
            if (e + u < e_end) {
                acc.x = fmaf(vu, x[u].x, acc.x);
                acc.y = fmaf(vu, x[u].y, acc.y);
                acc.z = fmaf(vu, x[u].z, acc.z);
                acc.w = fmaf(vu, x[u].w, acc.w);
            }
        }
        e += 8;
    }

    // one 16 B store per lane; a sub's 16 lanes = contiguous 256 B row.
    // Also zeroes empty rows (e == e_end path falls through with acc=0).
    if (valid)
        ((float4*)out)[(r << 4) + fl] = acc;
}

extern "C" void kernel_launch(void* const* d_in, const int* in_sizes, int n_in,
                              void* d_out, int out_size, void* d_ws, size_t ws_size,
                              hipStream_t stream) {
    const float* seq  = (const float*)d_in[0];
    const float* vals = (const float*)d_in[1];
    const int*   rows = (const int*)d_in[2];
    const int*   cols = (const int*)d_in[3];
    float*       out  = (float*)d_out;

    const int n_edges = in_sizes[1];            // E
    const int n_nodes = out_size / 64;          // N (out is [1,N,64])

    const int waves  = (n_nodes + 3) / 4;       // one row per 16-lane sub
    const int blocks = (waves + WPB - 1) / WPB;
    spmm_kernel<<<blocks, 256, 0, stream>>>(
        (const float4*)seq, vals, cols, rows, out, n_nodes, n_edges);
}

// Round 9
// 98.143 us; speedup vs baseline: 1.2432x; 1.2432x over previous
//
#include <hip/hip_runtime.h>

// COO SpMM: out[r,:] = sum_e vals[e] * seq[cols[e],:], rows sorted.
// N=50000, E=1.25M, D=64, fp32 in/out.
//
// R1-R5: gather-geometry ladder               -> 56.6 .. 53 us
// R6: RPS=1, depth 8, fp32 direct             -> ~41 us spmm
// R7: bf16 gather table (6.4 MB)              -> harness 98.6 (best total)
// R8: concurrent feature-split halves         -> 111 FAIL (XCD parity myth)
// R9: temporal column partition (2 phases)    -> 126 FAIL (scan dominates)
// R10: halved vmem instrs + meta prefetch     -> 103 (no spmm gain)
// R11: 32-lane subs                           -> 113.6 FAIL (geometry)
// R12: fp32 direct, PROFILED: spmm 45.2, FETCH 131MB (2 lines/edge)
// R13: in-kernel binary search                -> 122 FAIL: 21-deep dependent
//      cold-miss chain at kernel start, un-hidable, +8-10 us.
//
// MODEL: gathers served ~7.8 TB/s aggregate; L2-miss fraction ~ table
//   size; bf16 table (1 line/edge) is the best measured spmm (~41 us).
//   All residency/geometry/partitioning deviations regressed. Floor =
//   R7 spmm + minimal prep + minimal dispatch count.
// R14 (this): R7's spmm VERBATIM + merged single prep dispatch
//   (cvt + row_ptr by block-range, proven in R8-R10). 3 dispatches -> 2.

#define WPB 4               // waves per 256-thread block

// Merged prep:
//   blocks [0, cvt_blocks):  fp32 seq -> packed bf16 seqb[N][16 x uint2]
//   blocks [cvt_blocks, ..): row_start[t] = first edge e with rows[e] >= t
__global__ __launch_bounds__(256) void prep_kernel(
    const float4* __restrict__ seq,       // [N*16] float4 (= [N][64] fp32)
    uint2*        __restrict__ seqb,      // [N][16] uint2 (128 B per node)
    const int*    __restrict__ rows,
    int*          __restrict__ row_start,
    int n_nodes, int n_edges, int cvt_blocks)
{
    if ((int)blockIdx.x < cvt_blocks) {
        const int t = blockIdx.x * 256 + threadIdx.x;   // one float4 -> one uint2
        if (t >= n_nodes * 16) return;
        const float4 f = seq[t];
        const unsigned ux = __float_as_uint(f.x), uy = __float_as_uint(f.y);
        const unsigned uz = __float_as_uint(f.z), uw = __float_as_uint(f.w);
        const unsigned bx = (ux + 0x7FFFu + ((ux >> 16) & 1u)) >> 16;
        const unsigned by = (uy + 0x7FFFu + ((uy >> 16) & 1u)) >> 16;
        const unsigned bz = (uz + 0x7FFFu + ((uz >> 16) & 1u)) >> 16;
        const unsigned bw = (uw + 0x7FFFu + ((uw >> 16) & 1u)) >> 16;
        uint2 o;
        o.x = bx | (by << 16);
        o.y = bz | (bw << 16);
        seqb[t] = o;
    } else {
        const int e = (blockIdx.x - cvt_blocks) * 256 + threadIdx.x;
        if (e >= n_edges) return;
        const int r    = rows[e];
        const int prev = (e == 0) ? -1 : rows[e - 1];
        for (int t = prev + 1; t <= r; ++t) row_start[t] = e;
        if (e == n_edges - 1)
            for (int t = r + 1; t <= n_nodes; ++t) row_start[t] = n_edges;
    }
}

// R7's spmm, verbatim (best measured: ~41 us).
__global__ __launch_bounds__(256) void spmm_kernel(
    const uint2* __restrict__ seqb,       // [N][16] packed bf16 (128 B/row)
    const float* __restrict__ vals,       // [E]
    const int*   __restrict__ cols,       // [E]
    const int*   __restrict__ row_start,  // [N+1]
    float*       __restrict__ out,        // [N, 64]
    int n_nodes, int n_edges)
{
    const int lane = threadIdx.x & 63;
    const int sub  = lane >> 4;           // 16-lane sub-wave id (0..3)
    const int fl   = lane & 15;           // feature quad: floats 4*fl..4*fl+3
    const int wave = blockIdx.x * WPB + (threadIdx.x >> 6);

    const int r = wave * 4 + sub;         // one row per sub
    if (wave * 4 >= n_nodes) return;      // wave-uniform exit
    const bool valid = (r < n_nodes);

    int e = 0, e_end = 0;
    if (valid) {
        e     = row_start[r];
        e_end = row_start[r + 1];
    }

    float4 acc = make_float4(0.f, 0.f, 0.f, 0.f);

    while (__any(e < e_end)) {
        // coalesced metadata: next 16 edges of this sub
        int cidx = e + fl;
        cidx = (cidx < 0) ? 0 : (cidx >= n_edges ? n_edges - 1 : cidx);
        const int   c = cols[cidx];
        const float v = vals[cidx];

        // whole chunk issued in one round: 16 independent gathers;
        // a sub's 16 lanes x 8 B = one 128 B row = 1 line/edge.
        uint2 x[16];
#pragma unroll
        for (int u = 0; u < 16; ++u) {
            const int cu = __shfl(c, (sub << 4) | u);   // sub-local broadcast
            if (e + u < e_end)
                x[u] = seqb[(cu << 4) + fl];            // 8 B: 4 bf16 feats
        }
#pragma unroll
        for (int u = 0; u < 16; ++u) {
            const float vu = __shfl(v, (sub << 4) | u);
            if (e + u < e_end) {
                const float f0 = __uint_as_float(x[u].x << 16);
                const float f1 = __uint_as_float(x[u].x & 0xFFFF0000u);
                const float f2 = __uint_as_float(x[u].y << 16);
                const float f3 = __uint_as_float(x[u].y & 0xFFFF0000u);
                acc.x = fmaf(vu, f0, acc.x);
                acc.y = fmaf(vu, f1, acc.y);
                acc.z = fmaf(vu, f2, acc.z);
                acc.w = fmaf(vu, f3, acc.w);
            }
        }
        e += 16;
    }

    // exactly one 256 B store per row; also zeroes empty rows
    if (valid)
        ((float4*)out)[(r << 4) + fl] = acc;
}

extern "C" void kernel_launch(void* const* d_in, const int* in_sizes, int n_in,
                              void* d_out, int out_size, void* d_ws, size_t ws_size,
                              hipStream_t stream) {
    const float* seq  = (const float*)d_in[0];
    const float* vals = (const float*)d_in[1];
    const int*   rows = (const int*)d_in[2];
    const int*   cols = (const int*)d_in[3];
    float*       out  = (float*)d_out;

    const int n_edges = in_sizes[1];            // E
    const int n_nodes = out_size / 64;          // N (out is [1,N,64])

    // ws layout: [row_start: (N+1) ints][pad to 256][seqb: N*128 B]
    int*   row_start = (int*)d_ws;
    size_t off       = (((size_t)(n_nodes + 1) * 4 + 255) / 256) * 256;
    uint2* seqb      = (uint2*)((char*)d_ws + off);

    {
        const int cvt_blocks = (n_nodes * 16 + 255) / 256;
        const int rp_blocks  = (n_edges + 255) / 256;
        prep_kernel<<<cvt_blocks + rp_blocks, 256, 0, stream>>>(
            (const float4*)seq, seqb, rows, row_start,
            n_nodes, n_edges, cvt_blocks);
    }
    {
        const int waves  = (n_nodes + 3) / 4;   // one row per 16-lane sub
        const int blocks = (waves + WPB - 1) / WPB;
        spmm_kernel<<<blocks, 256, 0, stream>>>(
            seqb, vals, cols, row_start, out, n_nodes, n_edges);
    }
}